// Round 6
// baseline (336.660 us; speedup 1.0000x reference)
//
#include <hip/hip_runtime.h>
#include <math.h>

// AttentionDecoder: score_i = (Wk^T (Wq [cur;ctx])) . cand_i over N=200000,
// masked softmax -> top-50 threshold filter -> renormalize -> log, plus
// bit-exact jax.random.categorical(key(42)) via partitionable-threefry gumbel.
// R6: 3 kernels. prep | score(+NLOG out, LDS hist -> 32 global copies,
// Z -> 8 slots, last block: Z-sum + chunked top-down scan -> u_lo) |
// gather(+select, scatter-rewrite included entries, categorical).
// ghist needs no zeroing: ws poison is 0xAAAAAAAA, subtracted in the scan.

#define CAP 4096
#define NEG_INF (-__builtin_inff())
#define NHCOPY 32
#define NZSLOT 8

// order-preserving float->uint mapping (monotone increasing)
__device__ __forceinline__ unsigned int f2ord(float f){
  unsigned int b = __float_as_uint(f);
  return (b & 0x80000000u) ? ~b : (b | 0x80000000u);
}
__device__ __forceinline__ unsigned int rotl32(unsigned int x, int d){
  return (x << d) | (x >> (32 - d));
}

// JAX partitionable threefry, key (0,42): x0=idx>>32(=0), x1=idx; bits=w0^w1.
// gumbel = -log(-log(u)), u = bitcast((bits>>9)|0x3f800000)-1 clamped to tiny.
__device__ float gumbel_from_idx(unsigned int idx){
  unsigned int x0 = 0u, x1 = idx;
  const unsigned int ks0 = 0u, ks1 = 42u;
  const unsigned int ks2 = 0u ^ 42u ^ 0x1BD11BDAu;
  x0 += ks0; x1 += ks1;
#define TF_RND(r) { x0 += x1; x1 = rotl32(x1, (r)); x1 ^= x0; }
  TF_RND(13) TF_RND(15) TF_RND(26) TF_RND(6)
  x0 += ks1; x1 += ks2 + 1u;
  TF_RND(17) TF_RND(29) TF_RND(16) TF_RND(24)
  x0 += ks2; x1 += ks0 + 2u;
  TF_RND(13) TF_RND(15) TF_RND(26) TF_RND(6)
  x0 += ks0; x1 += ks1 + 3u;
  TF_RND(17) TF_RND(29) TF_RND(16) TF_RND(24)
  x0 += ks1; x1 += ks2 + 4u;
  TF_RND(13) TF_RND(15) TF_RND(26) TF_RND(6)
  x0 += ks2; x1 += ks0 + 5u;
#undef TF_RND
  unsigned int bits = x0 ^ x1;
  unsigned int fb = (bits >> 9) | 0x3f800000u;
  float f = __uint_as_float(fb) - 1.0f;
  float u = (f < 1.17549435e-38f) ? 1.17549435e-38f : f;
  return -logf(-logf(u));
}

// scal layout (uint/float aliased):
// [0]=nbuf [1]=u_lo [3]=Z [6]=done_score [7]=done_gather [8..15]=zslots(float)
__global__ void k_prep(const float* __restrict__ cur, const float* __restrict__ ctx,
                       const float* __restrict__ Wq, const float* __restrict__ Wk,
                       float* __restrict__ v, unsigned int* __restrict__ scal_u){
  __shared__ float comb[256];
  __shared__ float q[128];
  int t = threadIdx.x;
  if (t < 16) scal_u[t] = 0u;
  comb[t] = (t < 128) ? cur[t] : ctx[t - 128];
  __syncthreads();
  if (t < 128){
    float acc = 0.f;
    const float* row = Wq + t * 256;
    for (int j = 0; j < 256; ++j) acc = fmaf(row[j], comb[j], acc);
    q[t] = acc;
  }
  __syncthreads();
  if (t < 128){
    float acc = 0.f;
    for (int h = 0; h < 128; ++h) acc = fmaf(q[h], Wk[h * 128 + t], acc);
    v[t] = acc;
  }
}

// GEMV + hist + Z. Half-wave per row (32 lanes x float4 = 512B row), 16 rows
// per wave, 64 rows per block, one tile per block (full occupancy, 8 loads in
// flight). Writes raw scores to ws, NLOG to out. LDS hist flushed to global
// copy blockIdx&31 (poison-offset handled in scan). Last block: Z + scan.
__global__ __launch_bounds__(256) void k_score(const float* __restrict__ cand,
    const int* __restrict__ mask, const float* __restrict__ v,
    float* __restrict__ scores, float* __restrict__ out,
    unsigned int* __restrict__ ghist, unsigned int* __restrict__ scal_u,
    int N, int ktop){
  __shared__ unsigned int lhist[2048];
  __shared__ float wsum[4];
  __shared__ int is_last;
  const float NLOG = logf(1e-10f);
  int t = threadIdx.x;
  int lane = t & 63, wave = t >> 6;
  int hi = lane >> 5, hl = lane & 31;
  for (int k = t; k < 2048; k += 256) lhist[k] = 0u;
  __syncthreads();
  float4 v4 = ((const float4*)v)[hl];
  const float4* cp = (const float4*)cand;
  int base = (blockIdx.x * 4 + wave) * 16;
  float p[8];
  #pragma unroll
  for (int k = 0; k < 8; ++k){
    int r = base + 2 * k + hi;
    r = (r < N) ? r : (N - 1);                 // clamp: load stays unconditional
    float4 c = cp[(size_t)r * 32 + hl];
    p[k] = fmaf(c.x, v4.x, fmaf(c.y, v4.y, fmaf(c.z, v4.z, c.w * v4.w)));
  }
  #pragma unroll
  for (int k = 0; k < 8; ++k){                 // 8 independent 5-shfl chains
    p[k] += __shfl_xor(p[k], 1, 64);
    p[k] += __shfl_xor(p[k], 2, 64);
    p[k] += __shfl_xor(p[k], 4, 64);
    p[k] += __shfl_xor(p[k], 8, 64);
    p[k] += __shfl_xor(p[k], 16, 64);
  }
  float sv = p[0];
  #pragma unroll
  for (int k = 1; k < 8; ++k) sv = (hl == k) ? p[k] : sv;
  float ez = 0.f;
  if (hl < 8){                                 // writer lanes
    int r = base + 2 * hl + hi;
    if (r < N){
      int m = mask[r];
      float s = m ? sv : NEG_INF;
      scores[r] = s;
      if (m){
        atomicAdd(&lhist[f2ord(s) >> 21], 1u);
        ez = expf(s);                          // |s| bounded ~60: no overflow
      }
    }
  }
  int rr = blockIdx.x * 64 + t;                // default output value
  if (t < 64 && rr < N) out[rr] = NLOG;
  #pragma unroll
  for (int off = 32; off; off >>= 1) ez += __shfl_xor(ez, off, 64);
  if (lane == 0) wsum[wave] = ez;
  __syncthreads();
  unsigned int hbase = (blockIdx.x & (NHCOPY - 1)) * 2048u;
  for (int k = t; k < 2048; k += 256){
    unsigned int c = lhist[k];
    if (c) atomicAdd(&ghist[hbase + k], c);
  }
  if (t == 0)
    atomicAdd((float*)scal_u + 8 + (blockIdx.x & (NZSLOT - 1)),
              wsum[0] + wsum[1] + wsum[2] + wsum[3]);
  __syncthreads();
  if (t == 0){
    __threadfence();
    unsigned int old = atomicAdd(&scal_u[6], 1u);
    is_last = (old == gridDim.x - 1u);
  }
  __syncthreads();
  if (!is_last) return;
  __threadfence();                             // acquire: see all flushes
  float* scal_f = (float*)scal_u;
  if (t == 0){
    float Z = 0.f;
    for (int c = 0; c < NZSLOT; ++c) Z += scal_f[8 + c];
    scal_f[3] = Z;
  }
  // ---- chunked top-down suffix scan over 32 poisoned hist copies ----
  __shared__ unsigned int suf[256];
  __shared__ int bsel_sh;
  if (t == 0) bsel_sh = 0;
  unsigned int cumAbove = 0;
  unsigned int ku = (unsigned int)ktop;
  for (int chunk = 7; chunk >= 0; --chunk){
    int b = chunk * 256 + t;
    unsigned int s = 0;
    for (int c = 0; c < NHCOPY; ++c) s += ghist[c * 2048 + b] - 0xAAAAAAAAu;
    suf[t] = s;
    __syncthreads();
    for (int d = 1; d < 256; d <<= 1){
      unsigned int add = (t + d < 256) ? suf[t + d] : 0u;
      __syncthreads();
      suf[t] += add;
      __syncthreads();
    }
    unsigned int tot = suf[0];                 // uniform
    int found = (cumAbove + tot >= ku);
    if (found){
      unsigned int st = cumAbove + suf[t];
      unsigned int sn = (t < 255) ? (cumAbove + suf[t + 1]) : cumAbove;
      if (st >= ku && sn < ku) bsel_sh = b;    // unique writer
    }
    __syncthreads();
    if (found) break;
    cumAbove += tot;
  }
  if (t == 0) scal_u[1] = ((unsigned int)bsel_sh) << 21;   // u_lo
}

// Gather entries >= bin edge (superset of top-ktop); last block: exact
// rank-select, denom, scatter-rewrite included outputs, gumbel categorical.
__global__ __launch_bounds__(256) void k_gather(const float* __restrict__ scores,
    unsigned int* __restrict__ scal_u, unsigned int* __restrict__ buf_idx,
    float* __restrict__ buf_s, float* __restrict__ out, int N, int ktop){
  int t = threadIdx.x;
  unsigned int u_lo = scal_u[1];
  int i0 = (blockIdx.x * 256 + t) * 4;
  if (i0 + 3 < N){
    float4 s4 = *(const float4*)(scores + i0);
    float ss[4] = {s4.x, s4.y, s4.z, s4.w};
    #pragma unroll
    for (int e = 0; e < 4; ++e){
      float s = ss[e];
      if (s > NEG_INF && f2ord(s) >= u_lo){
        unsigned int pos = atomicAdd(&scal_u[0], 1u);
        if (pos < CAP){ buf_idx[pos] = (unsigned int)(i0 + e); buf_s[pos] = s; }
      }
    }
  } else {
    for (int e = 0; e < 4; ++e){
      int i = i0 + e;
      if (i < N){
        float s = scores[i];
        if (s > NEG_INF && f2ord(s) >= u_lo){
          unsigned int pos = atomicAdd(&scal_u[0], 1u);
          if (pos < CAP){ buf_idx[pos] = (unsigned int)i; buf_s[pos] = s; }
        }
      }
    }
  }
  __syncthreads();
  __shared__ int is_last;
  if (t == 0){
    __threadfence();
    unsigned int old = atomicAdd(&scal_u[7], 1u);
    is_last = (old == gridDim.x - 1u);
  }
  __syncthreads();
  if (!is_last) return;
  __threadfence();
  // ---- exact select + output rewrite + categorical ----
  float* scal_f = (float*)scal_u;
  __shared__ float s_lds[CAP];
  __shared__ float thr_sh;
  __shared__ float wred[4];
  __shared__ float rv[4], rl[4];
  __shared__ unsigned int ri[4];
  int C = (int)scal_u[0]; if (C > CAP) C = CAP;
  for (int j = t; j < C; j += 256) s_lds[j] = buf_s[j];
  if (t == 0) thr_sh = NEG_INF;
  __syncthreads();
  if (C > ktop){
    for (int j = t; j < C; j += 256){
      float sj = s_lds[j];
      int g = 0, e = 0;
      for (int k2 = 0; k2 < C; ++k2){
        float sk = s_lds[k2];
        g += (sk > sj);
        e += (sk == sj);
      }
      if (g < ktop && g + e >= ktop) thr_sh = sj;   // all writers same value
    }
  }
  __syncthreads();
  float s_thr = thr_sh;
  float Z = scal_f[3];
  float part = 0.f;
  for (int j = t; j < C; j += 256){
    float sj = s_lds[j];
    if (sj >= s_thr) part += expf(sj);
  }
  #pragma unroll
  for (int off = 32; off; off >>= 1) part += __shfl_xor(part, off, 64);
  int wave = t >> 6, lane = t & 63;
  if (lane == 0) wred[wave] = part;
  __syncthreads();
  float T = wred[0] + wred[1] + wred[2] + wred[3];
  float D = T + 1e-10f * Z;                 // = Z*(sum_top p + 1e-10)
  float lnD = logf(D);
  // rewrite the included entries (everything else already NLOG from k_score)
  for (int j = t; j < C; j += 256){
    float sj = s_lds[j];
    if (sj >= s_thr) out[buf_idx[j]] = logf(expf(sj - lnD) + 1e-10f);
  }
  float bestv = NEG_INF, bestlogit = NEG_INF;
  unsigned int bestidx = 0xFFFFFFFFu;
  for (int j = t; j < C; j += 256){
    float sj = s_lds[j];
    if (sj >= s_thr){
      unsigned int idx = buf_idx[j];
      float logit = sj - lnD;               // log(filtered)
      float val = logit + gumbel_from_idx(idx);
      if (val > bestv || (val == bestv && idx < bestidx)){
        bestv = val; bestlogit = logit; bestidx = idx;
      }
    }
  }
  #pragma unroll
  for (int off = 32; off; off >>= 1){
    float ov = __shfl_xor(bestv, off, 64);
    float ol = __shfl_xor(bestlogit, off, 64);
    unsigned int oi = (unsigned int)__shfl_xor((int)bestidx, off, 64);
    if (ov > bestv || (ov == bestv && oi < bestidx)){
      bestv = ov; bestlogit = ol; bestidx = oi;
    }
  }
  if (lane == 0){ rv[wave] = bestv; rl[wave] = bestlogit; ri[wave] = bestidx; }
  __syncthreads();
  if (t == 0){
    for (int w = 1; w < 4; ++w){
      if (rv[w] > rv[0] || (rv[w] == rv[0] && ri[w] < ri[0])){
        rv[0] = rv[w]; rl[0] = rl[w]; ri[0] = ri[w];
      }
    }
    out[N] = rl[0];                 // log_prob_action
    out[N + 1] = (float)ri[0];      // action_idx
  }
}

extern "C" void kernel_launch(void* const* d_in, const int* in_sizes, int n_in,
                              void* d_out, int out_size, void* d_ws, size_t ws_size,
                              hipStream_t stream){
  const float* cur  = (const float*)d_in[0];
  const float* ctx  = (const float*)d_in[1];
  const float* cand = (const float*)d_in[2];
  const float* Wq   = (const float*)d_in[3];
  const float* Wk   = (const float*)d_in[4];
  const int*   mask = (const int*)d_in[5];
  int N = in_sizes[5];
  float* out = (float*)d_out;

  char* ws = (char*)d_ws;
  unsigned int* scal_u  = (unsigned int*)ws;                     // 64 B (pad 256)
  unsigned int* ghist   = (unsigned int*)(ws + 256);             // 32*2048*4 = 256 KB
  float*        v       = (float*)(ws + 256 + 262144);           // 512 B
  float*        scores  = (float*)(ws + 256 + 262144 + 512);     // N*4 (16B-aligned)
  char*         bufbase = ws + 256 + 262144 + 512 + 800000;
  unsigned int* buf_idx = (unsigned int*)bufbase;                // CAP*4
  float*        buf_s   = (float*)(bufbase + CAP * 4);           // CAP*4

  int ktop = N / 2; if (ktop < 1) ktop = 1; if (ktop > 50) ktop = 50;

  int g_score  = (N + 63) / 64;       // one 64-row tile per block
  int g_gather = (N + 1023) / 1024;   // 4 elems/thread

  k_prep<<<1, 256, 0, stream>>>(cur, ctx, Wq, Wk, v, scal_u);
  k_score<<<g_score, 256, 0, stream>>>(cand, mask, v, scores, out, ghist, scal_u, N, ktop);
  k_gather<<<g_gather, 256, 0, stream>>>(scores, scal_u, buf_idx, buf_s, out, N, ktop);
}

// Round 7
// 206.464 us; speedup vs baseline: 1.6306x; 1.6306x over previous
//
#include <hip/hip_runtime.h>
#include <math.h>

// AttentionDecoder: score_i = (Wk^T (Wq [cur;ctx])) . cand_i over N=200000,
// masked softmax -> top-50 threshold filter -> renormalize -> log, plus
// bit-exact jax.random.categorical(key(42)) via partitionable-threefry gumbel.
// R7: 4 kernels. prep | score (PURE GEMV, loads batched before FMAs for MLP;
// writes scores->ws and NLOG default->out) | hist(+Z+scan, 196 blocks) |
// gather(+select, scatter-rewrite included entries, categorical).
// Lesson from R6: same-address global atomics cost ~50ns each serialized ->
// keep every same-address atomic count <= ~200 per kernel (done-counters at
// 3125 blocks cost 156us). k_score therefore has NO atomics.

#define CAP 4096
#define NEG_INF (-__builtin_inff())

// order-preserving float->uint mapping (monotone increasing)
__device__ __forceinline__ unsigned int f2ord(float f){
  unsigned int b = __float_as_uint(f);
  return (b & 0x80000000u) ? ~b : (b | 0x80000000u);
}
__device__ __forceinline__ unsigned int rotl32(unsigned int x, int d){
  return (x << d) | (x >> (32 - d));
}

// JAX partitionable threefry, key (0,42): x0=idx>>32(=0), x1=idx; bits=w0^w1.
// gumbel = -log(-log(u)), u = bitcast((bits>>9)|0x3f800000)-1 clamped to tiny.
__device__ float gumbel_from_idx(unsigned int idx){
  unsigned int x0 = 0u, x1 = idx;
  const unsigned int ks0 = 0u, ks1 = 42u;
  const unsigned int ks2 = 0u ^ 42u ^ 0x1BD11BDAu;
  x0 += ks0; x1 += ks1;
#define TF_RND(r) { x0 += x1; x1 = rotl32(x1, (r)); x1 ^= x0; }
  TF_RND(13) TF_RND(15) TF_RND(26) TF_RND(6)
  x0 += ks1; x1 += ks2 + 1u;
  TF_RND(17) TF_RND(29) TF_RND(16) TF_RND(24)
  x0 += ks2; x1 += ks0 + 2u;
  TF_RND(13) TF_RND(15) TF_RND(26) TF_RND(6)
  x0 += ks0; x1 += ks1 + 3u;
  TF_RND(17) TF_RND(29) TF_RND(16) TF_RND(24)
  x0 += ks1; x1 += ks2 + 4u;
  TF_RND(13) TF_RND(15) TF_RND(26) TF_RND(6)
  x0 += ks2; x1 += ks0 + 5u;
#undef TF_RND
  unsigned int bits = x0 ^ x1;
  unsigned int fb = (bits >> 9) | 0x3f800000u;
  float f = __uint_as_float(fb) - 1.0f;
  float u = (f < 1.17549435e-38f) ? 1.17549435e-38f : f;
  return -logf(-logf(u));
}

// scal layout (uint/float aliased):
// [0]=nbuf [1]=u_lo [3]=Z [6]=done_hist [7]=done_gather
__global__ void k_prep(const float* __restrict__ cur, const float* __restrict__ ctx,
                       const float* __restrict__ Wq, const float* __restrict__ Wk,
                       float* __restrict__ v, unsigned int* __restrict__ hist,
                       unsigned int* __restrict__ scal_u){
  __shared__ float comb[256];
  __shared__ float q[128];
  int t = threadIdx.x;
  for (int k = t; k < 2048; k += 256) hist[k] = 0u;
  if (t < 16) scal_u[t] = 0u;
  comb[t] = (t < 128) ? cur[t] : ctx[t - 128];
  __syncthreads();
  if (t < 128){
    float acc = 0.f;
    const float* row = Wq + t * 256;
    for (int j = 0; j < 256; ++j) acc = fmaf(row[j], comb[j], acc);
    q[t] = acc;
  }
  __syncthreads();
  if (t < 128){
    float acc = 0.f;
    for (int h = 0; h < 128; ++h) acc = fmaf(q[h], Wk[h * 128 + t], acc);
    v[t] = acc;
  }
}

// PURE GEMV. Half-wave per row (32 lanes x float4 = 512B row), 16 rows/wave,
// 64 rows/block, one tile per block. All 8 loads issued before any FMA
// (c[8] array) -> 8 global_load_dwordx4 in flight per wave. No atomics.
__global__ __launch_bounds__(256) void k_score(const float* __restrict__ cand,
    const int* __restrict__ mask, const float* __restrict__ v,
    float* __restrict__ scores, float* __restrict__ out, int N){
  const float NLOG = logf(1e-10f);
  int t = threadIdx.x;
  int lane = t & 63, wave = t >> 6;
  int hi = lane >> 5, hl = lane & 31;
  float4 v4 = ((const float4*)v)[hl];
  const float4* cp = (const float4*)cand;
  int base = (blockIdx.x * 4 + wave) * 16;
  float4 c[8];
  #pragma unroll
  for (int k = 0; k < 8; ++k){                 // phase 1: 8 loads in flight
    int r = base + 2 * k + hi;
    r = (r < N) ? r : (N - 1);                 // clamp: load stays unconditional
    c[k] = cp[(size_t)r * 32 + hl];
  }
  float p[8];
  #pragma unroll
  for (int k = 0; k < 8; ++k)                  // phase 2: consume
    p[k] = fmaf(c[k].x, v4.x, fmaf(c[k].y, v4.y, fmaf(c[k].z, v4.z, c[k].w * v4.w)));
  #pragma unroll
  for (int k = 0; k < 8; ++k){                 // 8 independent 5-shfl chains
    p[k] += __shfl_xor(p[k], 1, 64);
    p[k] += __shfl_xor(p[k], 2, 64);
    p[k] += __shfl_xor(p[k], 4, 64);
    p[k] += __shfl_xor(p[k], 8, 64);
    p[k] += __shfl_xor(p[k], 16, 64);
  }
  float sv = p[0];
  #pragma unroll
  for (int k = 1; k < 8; ++k) sv = (hl == k) ? p[k] : sv;
  if (hl < 8){                                 // writer lanes
    int r = base + 2 * hl + hi;
    if (r < N) scores[r] = mask[r] ? sv : NEG_INF;
  }
  int rr = blockIdx.x * 64 + t;                // default output value
  if (t < 64 && rr < N) out[rr] = NLOG;
}

// 0.8MB pass (196 blocks): LDS histogram + Z; flush <=196 atomics/address;
// last block does the suffix scan -> u_lo.
__global__ __launch_bounds__(256) void k_hist(const float* __restrict__ scores,
    unsigned int* __restrict__ hist, unsigned int* __restrict__ scal_u,
    int N, int ktop){
  __shared__ unsigned int lhist[2048];
  __shared__ float wsum[4];
  __shared__ int is_last;
  int t = threadIdx.x;
  int lane = t & 63, wave = t >> 6;
  for (int k = t; k < 2048; k += 256) lhist[k] = 0u;
  __syncthreads();
  float ez = 0.f;
  int i0 = (blockIdx.x * 256 + t) * 4;
  if (i0 + 3 < N){
    float4 s4 = *(const float4*)(scores + i0);
    float ss[4] = {s4.x, s4.y, s4.z, s4.w};
    #pragma unroll
    for (int e = 0; e < 4; ++e){
      if (ss[e] > NEG_INF){
        atomicAdd(&lhist[f2ord(ss[e]) >> 21], 1u);
        ez += expf(ss[e]);                     // |s| bounded ~60: no overflow
      }
    }
  } else {
    for (int e = 0; e < 4; ++e){
      int i = i0 + e;
      if (i < N){
        float s = scores[i];
        if (s > NEG_INF){ atomicAdd(&lhist[f2ord(s) >> 21], 1u); ez += expf(s); }
      }
    }
  }
  #pragma unroll
  for (int off = 32; off; off >>= 1) ez += __shfl_xor(ez, off, 64);
  if (lane == 0) wsum[wave] = ez;
  __syncthreads();
  for (int k = t; k < 2048; k += 256){
    unsigned int c = lhist[k];
    if (c) atomicAdd(&hist[k], c);
  }
  if (t == 0) atomicAdd((float*)scal_u + 3, wsum[0] + wsum[1] + wsum[2] + wsum[3]);
  __syncthreads();
  if (t == 0){
    __threadfence();
    unsigned int old = atomicAdd(&scal_u[6], 1u);
    is_last = (old == gridDim.x - 1u);
  }
  __syncthreads();
  if (!is_last) return;
  __threadfence();
  // ---- histogram suffix scan -> u_lo (bin lower edge of ktop-th score) ----
  __shared__ unsigned int suf[256];
  __shared__ int csel_sh;
  unsigned int csum = 0;
  for (int k = 0; k < 8; ++k) csum += hist[t * 8 + k];
  suf[t] = csum;
  if (t == 0) csel_sh = -1;
  __syncthreads();
  for (int d = 1; d < 256; d <<= 1){
    unsigned int add = (t + d < 256) ? suf[t + d] : 0u;
    __syncthreads();
    suf[t] += add;
    __syncthreads();
  }
  unsigned int st = suf[t];
  unsigned int sn = (t < 255) ? suf[t + 1] : 0u;
  if (st >= (unsigned)ktop && sn < (unsigned)ktop) csel_sh = t;   // unique
  __syncthreads();
  if (t == 0){
    int b_sel = 0;
    if (csel_sh >= 0){
      int c = csel_sh;
      unsigned int cum = (c < 255) ? suf[c + 1] : 0u;
      for (int b = 8 * c + 7; b >= 8 * c; --b){
        cum += hist[b];
        if (cum >= (unsigned)ktop){ b_sel = b; break; }
      }
    }
    scal_u[1] = ((unsigned int)b_sel) << 21;
  }
}

// Gather entries >= bin edge (superset of top-ktop); last block: exact
// rank-select, denom, scatter-rewrite included outputs, gumbel categorical.
__global__ __launch_bounds__(256) void k_gather(const float* __restrict__ scores,
    unsigned int* __restrict__ scal_u, unsigned int* __restrict__ buf_idx,
    float* __restrict__ buf_s, float* __restrict__ out, int N, int ktop){
  int t = threadIdx.x;
  unsigned int u_lo = scal_u[1];
  int i0 = (blockIdx.x * 256 + t) * 4;
  if (i0 + 3 < N){
    float4 s4 = *(const float4*)(scores + i0);
    float ss[4] = {s4.x, s4.y, s4.z, s4.w};
    #pragma unroll
    for (int e = 0; e < 4; ++e){
      float s = ss[e];
      if (s > NEG_INF && f2ord(s) >= u_lo){
        unsigned int pos = atomicAdd(&scal_u[0], 1u);
        if (pos < CAP){ buf_idx[pos] = (unsigned int)(i0 + e); buf_s[pos] = s; }
      }
    }
  } else {
    for (int e = 0; e < 4; ++e){
      int i = i0 + e;
      if (i < N){
        float s = scores[i];
        if (s > NEG_INF && f2ord(s) >= u_lo){
          unsigned int pos = atomicAdd(&scal_u[0], 1u);
          if (pos < CAP){ buf_idx[pos] = (unsigned int)i; buf_s[pos] = s; }
        }
      }
    }
  }
  __syncthreads();
  __shared__ int is_last;
  if (t == 0){
    __threadfence();
    unsigned int old = atomicAdd(&scal_u[7], 1u);
    is_last = (old == gridDim.x - 1u);
  }
  __syncthreads();
  if (!is_last) return;
  __threadfence();
  // ---- exact select + output rewrite + categorical ----
  float* scal_f = (float*)scal_u;
  __shared__ float s_lds[CAP];
  __shared__ float thr_sh;
  __shared__ float wred[4];
  __shared__ float rv[4], rl[4];
  __shared__ unsigned int ri[4];
  int C = (int)scal_u[0]; if (C > CAP) C = CAP;
  for (int j = t; j < C; j += 256) s_lds[j] = buf_s[j];
  if (t == 0) thr_sh = NEG_INF;
  __syncthreads();
  if (C > ktop){
    for (int j = t; j < C; j += 256){
      float sj = s_lds[j];
      int g = 0, e = 0;
      for (int k2 = 0; k2 < C; ++k2){
        float sk = s_lds[k2];
        g += (sk > sj);
        e += (sk == sj);
      }
      if (g < ktop && g + e >= ktop) thr_sh = sj;   // all writers same value
    }
  }
  __syncthreads();
  float s_thr = thr_sh;
  float Z = scal_f[3];
  float part = 0.f;
  for (int j = t; j < C; j += 256){
    float sj = s_lds[j];
    if (sj >= s_thr) part += expf(sj);
  }
  #pragma unroll
  for (int off = 32; off; off >>= 1) part += __shfl_xor(part, off, 64);
  int wave = t >> 6, lane = t & 63;
  if (lane == 0) wred[wave] = part;
  __syncthreads();
  float T = wred[0] + wred[1] + wred[2] + wred[3];
  float D = T + 1e-10f * Z;                 // = Z*(sum_top p + 1e-10)
  float lnD = logf(D);
  // rewrite the included entries (everything else already NLOG from k_score)
  for (int j = t; j < C; j += 256){
    float sj = s_lds[j];
    if (sj >= s_thr) out[buf_idx[j]] = logf(expf(sj - lnD) + 1e-10f);
  }
  float bestv = NEG_INF, bestlogit = NEG_INF;
  unsigned int bestidx = 0xFFFFFFFFu;
  for (int j = t; j < C; j += 256){
    float sj = s_lds[j];
    if (sj >= s_thr){
      unsigned int idx = buf_idx[j];
      float logit = sj - lnD;               // log(filtered)
      float val = logit + gumbel_from_idx(idx);
      if (val > bestv || (val == bestv && idx < bestidx)){
        bestv = val; bestlogit = logit; bestidx = idx;
      }
    }
  }
  #pragma unroll
  for (int off = 32; off; off >>= 1){
    float ov = __shfl_xor(bestv, off, 64);
    float ol = __shfl_xor(bestlogit, off, 64);
    unsigned int oi = (unsigned int)__shfl_xor((int)bestidx, off, 64);
    if (ov > bestv || (ov == bestv && oi < bestidx)){
      bestv = ov; bestlogit = ol; bestidx = oi;
    }
  }
  if (lane == 0){ rv[wave] = bestv; rl[wave] = bestlogit; ri[wave] = bestidx; }
  __syncthreads();
  if (t == 0){
    for (int w = 1; w < 4; ++w){
      if (rv[w] > rv[0] || (rv[w] == rv[0] && ri[w] < ri[0])){
        rv[0] = rv[w]; rl[0] = rl[w]; ri[0] = ri[w];
      }
    }
    out[N] = rl[0];                 // log_prob_action
    out[N + 1] = (float)ri[0];      // action_idx
  }
}

extern "C" void kernel_launch(void* const* d_in, const int* in_sizes, int n_in,
                              void* d_out, int out_size, void* d_ws, size_t ws_size,
                              hipStream_t stream){
  const float* cur  = (const float*)d_in[0];
  const float* ctx  = (const float*)d_in[1];
  const float* cand = (const float*)d_in[2];
  const float* Wq   = (const float*)d_in[3];
  const float* Wk   = (const float*)d_in[4];
  const int*   mask = (const int*)d_in[5];
  int N = in_sizes[5];
  float* out = (float*)d_out;

  char* ws = (char*)d_ws;
  unsigned int* scal_u  = (unsigned int*)ws;                     // 64 B (pad 256)
  unsigned int* hist    = (unsigned int*)(ws + 256);             // 8192 B
  float*        v       = (float*)(ws + 256 + 8192);             // 512 B
  float*        scores  = (float*)(ws + 256 + 8192 + 512);       // N*4, 16B-aligned
  char*         bufbase = ws + 256 + 8192 + 512 + 800000;
  unsigned int* buf_idx = (unsigned int*)bufbase;                // CAP*4
  float*        buf_s   = (float*)(bufbase + CAP * 4);           // CAP*4

  int ktop = N / 2; if (ktop < 1) ktop = 1; if (ktop > 50) ktop = 50;

  int g_score = (N + 63) / 64;       // one 64-row tile per block
  int g_pass  = (N + 1023) / 1024;   // 4 elems/thread

  k_prep<<<1, 256, 0, stream>>>(cur, ctx, Wq, Wk, v, hist, scal_u);
  k_score<<<g_score, 256, 0, stream>>>(cand, mask, v, scores, out, N);
  k_hist<<<g_pass, 256, 0, stream>>>(scores, hist, scal_u, N, ktop);
  k_gather<<<g_pass, 256, 0, stream>>>(scores, scal_u, buf_idx, buf_s, out, N, ktop);
}